// Round 5
// baseline (1745.235 us; speedup 1.0000x reference)
//
#include <hip/hip_runtime.h>
#include <hip/hip_bf16.h>

#define LRELU(x) ((x) >= 0.f ? (x) : 0.01f * (x))

// ---------------------------------------------------------------------------
// Problem constants (match reference setup_inputs)
// ---------------------------------------------------------------------------
static constexpr int N_F = 50000, N_R = 25000;
static constexpr int E_FF = 400000, E_RR = 200000, E_RF = 400000;

// d_out layout (floats)
static constexpr size_t OFF_NF  = 0;                          // new_f  [50000,128]
static constexpr size_t OFF_NR  = OFF_NF + (size_t)N_F * 128; // new_r  [25000,128]
static constexpr size_t OFF_EFF = OFF_NR + (size_t)N_R * 128; // new_eff[400000,64]
static constexpr size_t OFF_ERR = OFF_EFF + (size_t)E_FF * 64;// new_err[200000,64]
static constexpr size_t OFF_ERF = OFF_ERR + (size_t)E_RR * 64;// new_erf[400000,64]

// workspace layout (floats)
static constexpr size_t WS_HF      = 0;                          // [50000,128]
static constexpr size_t WS_HR      = WS_HF + (size_t)N_F * 128;  // [25000,128]
static constexpr size_t WS_GFC_FF  = WS_HR + (size_t)N_R * 128;  // [50000,64]
static constexpr size_t WS_GFC_RF  = WS_GFC_FF + (size_t)N_F * 64;
static constexpr size_t WS_GRC_RR  = WS_GFC_RF + (size_t)N_F * 64; // [25000,64]
static constexpr size_t WS_DF_FFS  = WS_GRC_RR + (size_t)N_R * 64; // [50000]
static constexpr size_t WS_DF_FFD  = WS_DF_FFS + N_F;
static constexpr size_t WS_DF_RFD  = WS_DF_FFD + N_F;
static constexpr size_t WS_DR_RRS  = WS_DF_RFD + N_F;              // [25000]
static constexpr size_t WS_DR_RRD  = WS_DR_RRS + N_R;
static constexpr size_t WS_DR_RFS  = WS_DR_RRD + N_R;
static constexpr size_t WS_SFF     = WS_DR_RFS + N_R;              // [400000] raw lrelu scores
static constexpr size_t WS_SRR     = WS_SFF + E_FF;
static constexpr size_t WS_SRF     = WS_SRR + E_RR;
static constexpr size_t WS_WT      = WS_SRF + E_RF;                // [192]
static constexpr size_t WS_SUMF    = WS_WT + 192;                  // [50000]
static constexpr size_t WS_SUMR    = WS_SUMF + N_F;                // [25000]
static constexpr size_t WS_INT     = WS_SUMR + N_R;                // int region below

// int region offsets (in ints, relative to WS_INT)
static constexpr size_t I_CUR_FF = 0;                 // [50000]  (zeroed; hist cnt -> fill cursor)
static constexpr size_t I_CUR_RF = I_CUR_FF + N_F;    // [50000]
static constexpr size_t I_CUR_RR = I_CUR_RF + N_F;    // [25000]
static constexpr size_t I_ZERO_CNT = I_CUR_RR + N_R;  // 125000 ints zeroed
static constexpr size_t I_OFF_FF = I_ZERO_CNT;        // [50001]
static constexpr size_t I_OFF_RF = I_OFF_FF + N_F + 1;// [50001]
static constexpr size_t I_OFF_RR = I_OFF_RF + N_F + 1;// [25001]
static constexpr size_t I_EID_FF = I_OFF_RR + N_R + 1;// [400000]
static constexpr size_t I_EID_RF = I_EID_FF + E_FF;   // [400000]
static constexpr size_t I_EID_RR = I_EID_RF + E_RF;   // [200000]

// ---------------------------------------------------------------------------
// Tiny: w̃ = We @ a_e for the three edge types.
// ---------------------------------------------------------------------------
__global__ void wtilde_k(const float* __restrict__ We_ff, const float* __restrict__ We_rr,
                         const float* __restrict__ We_rf, const float* __restrict__ a_ff,
                         const float* __restrict__ a_rr, const float* __restrict__ a_rf,
                         float* __restrict__ wt) {
  int t = threadIdx.x;
  if (t >= 192) return;
  int grp = t >> 6, k = t & 63;
  const float* W = (grp == 0) ? We_ff : (grp == 1) ? We_rr : We_rf;
  const float* a = (grp == 0) ? a_ff + 256 : (grp == 1) ? a_rr + 256 : a_rf + 256;
  float s = 0.f;
  #pragma unroll 8
  for (int j = 0; j < 64; ++j) s += W[k * 64 + j] * a[j];
  wt[t] = s;
}

// ---------------------------------------------------------------------------
// CSR build: histogram -> exclusive scan (single block) -> fill
// ---------------------------------------------------------------------------
__global__ __launch_bounds__(256)
void hist_k(const int* __restrict__ dst, int* __restrict__ cnt, int E) {
  int e = (int)blockIdx.x * 256 + threadIdx.x;
  if (e < E) atomicAdd(&cnt[dst[e]], 1);
}

__global__ __launch_bounds__(1024)
void scan_k(int* __restrict__ cnt /*in: counts, out: cursor=start*/,
            int* __restrict__ off /*[n+1]*/, int n) {
  __shared__ int ls[1024];
  int t = threadIdx.x;
  int chunk = (n + 1023) / 1024;
  int beg = t * chunk;
  int end = beg + chunk < n ? beg + chunk : n;
  int s = 0;
  for (int i = beg; i < end; ++i) s += cnt[i];
  ls[t] = s;
  __syncthreads();
  for (int d = 1; d < 1024; d <<= 1) {
    int v = (t >= d) ? ls[t - d] : 0;
    __syncthreads();
    ls[t] += v;
    __syncthreads();
  }
  int run = (t == 0) ? 0 : ls[t - 1];
  for (int i = beg; i < end; ++i) {
    int c = cnt[i];
    off[i] = run;
    cnt[i] = run;   // cursor for fill
    run += c;
  }
  if (t == 1023) off[n] = ls[1023];
}

__global__ __launch_bounds__(256)
void fill_k(const int* __restrict__ dst, int* __restrict__ cur,
            int* __restrict__ eid, int E) {
  int e = (int)blockIdx.x * 256 + threadIdx.x;
  if (e < E) {
    int pos = atomicAdd(&cur[dst[e]], 1);
    eid[pos] = e;
  }
}

// ---------------------------------------------------------------------------
// Node projection GEMM fused with 3 attention dots:
//   C[M,128] = A[M,128] @ W[128,128];  d_i[m] = C[m,:] . a_i
// ---------------------------------------------------------------------------
__global__ __launch_bounds__(256)
void gemm_dot3_128(const float* __restrict__ A, const float* __restrict__ W,
                   const float* __restrict__ a0, const float* __restrict__ a1,
                   const float* __restrict__ a2, float* __restrict__ C,
                   float* __restrict__ d0, float* __restrict__ d1,
                   float* __restrict__ d2, int M) {
  constexpr int K = 128, N = 128, BM = 64, BK = 32;
  __shared__ float As[BM][BK + 1];
  __shared__ float Ws[BK][N];
  const int t = threadIdx.x;
  const int row0 = (int)blockIdx.x * BM;
  const int rg = t >> 4, cg = t & 15;
  const int r0 = rg * 4, c0 = cg * 4;

  float acc[4][8];
  #pragma unroll
  for (int i = 0; i < 4; ++i)
    #pragma unroll
    for (int j = 0; j < 8; ++j) acc[i][j] = 0.f;

  for (int kb = 0; kb < K; kb += BK) {
    #pragma unroll
    for (int u = 0; u < 2; ++u) {
      int id = t + u * 256;
      int ar = id >> 3, ac = (id & 7) * 4;
      float4 v = make_float4(0.f, 0.f, 0.f, 0.f);
      int grow = row0 + ar;
      if (grow < M) v = *reinterpret_cast<const float4*>(&A[(size_t)grow * K + kb + ac]);
      As[ar][ac] = v.x; As[ar][ac + 1] = v.y; As[ar][ac + 2] = v.z; As[ar][ac + 3] = v.w;
    }
    #pragma unroll
    for (int u = 0; u < 4; ++u) {
      int id = t + u * 256;
      int wr = id >> 5, wc = (id & 31) * 4;
      *reinterpret_cast<float4*>(&Ws[wr][wc]) =
          *reinterpret_cast<const float4*>(&W[(size_t)(kb + wr) * N + wc]);
    }
    __syncthreads();
    #pragma unroll
    for (int k = 0; k < BK; ++k) {
      float av[4] = {As[r0][k], As[r0 + 1][k], As[r0 + 2][k], As[r0 + 3][k]};
      float4 w0 = *reinterpret_cast<const float4*>(&Ws[k][c0]);
      float4 w1 = *reinterpret_cast<const float4*>(&Ws[k][c0 + 64]);
      #pragma unroll
      for (int i = 0; i < 4; ++i) {
        acc[i][0] += av[i] * w0.x; acc[i][1] += av[i] * w0.y;
        acc[i][2] += av[i] * w0.z; acc[i][3] += av[i] * w0.w;
        acc[i][4] += av[i] * w1.x; acc[i][5] += av[i] * w1.y;
        acc[i][6] += av[i] * w1.z; acc[i][7] += av[i] * w1.w;
      }
    }
    __syncthreads();
  }
  float4 a0l = *reinterpret_cast<const float4*>(&a0[c0]);
  float4 a0h = *reinterpret_cast<const float4*>(&a0[c0 + 64]);
  float4 a1l = *reinterpret_cast<const float4*>(&a1[c0]);
  float4 a1h = *reinterpret_cast<const float4*>(&a1[c0 + 64]);
  float4 a2l = *reinterpret_cast<const float4*>(&a2[c0]);
  float4 a2h = *reinterpret_cast<const float4*>(&a2[c0 + 64]);
  #pragma unroll
  for (int i = 0; i < 4; ++i) {
    int grow = row0 + r0 + i;
    if (grow < M) {
      *reinterpret_cast<float4*>(&C[(size_t)grow * N + c0]) =
          make_float4(acc[i][0], acc[i][1], acc[i][2], acc[i][3]);
      *reinterpret_cast<float4*>(&C[(size_t)grow * N + c0 + 64]) =
          make_float4(acc[i][4], acc[i][5], acc[i][6], acc[i][7]);
    }
    float p0 = acc[i][0] * a0l.x + acc[i][1] * a0l.y + acc[i][2] * a0l.z + acc[i][3] * a0l.w
             + acc[i][4] * a0h.x + acc[i][5] * a0h.y + acc[i][6] * a0h.z + acc[i][7] * a0h.w;
    float p1 = acc[i][0] * a1l.x + acc[i][1] * a1l.y + acc[i][2] * a1l.z + acc[i][3] * a1l.w
             + acc[i][4] * a1h.x + acc[i][5] * a1h.y + acc[i][6] * a1h.z + acc[i][7] * a1h.w;
    float p2 = acc[i][0] * a2l.x + acc[i][1] * a2l.y + acc[i][2] * a2l.z + acc[i][3] * a2l.w
             + acc[i][4] * a2h.x + acc[i][5] * a2h.y + acc[i][6] * a2h.z + acc[i][7] * a2h.w;
    #pragma unroll
    for (int off = 1; off < 16; off <<= 1) {
      p0 += __shfl_xor(p0, off);
      p1 += __shfl_xor(p1, off);
      p2 += __shfl_xor(p2, off);
    }
    if (cg == 0 && grow < M) { d0[grow] = p0; d1[grow] = p1; d2[grow] = p2; }
  }
}

// ---------------------------------------------------------------------------
// Plain tiled GEMM (edge-converter projections): C[M,64] = A[M,128] @ W[128,64]
// ---------------------------------------------------------------------------
__global__ __launch_bounds__(256)
void gemm_128x64(const float* __restrict__ A, const float* __restrict__ W,
                 float* __restrict__ C, int M) {
  constexpr int K = 128, N = 64, BM = 64, BK = 32;
  __shared__ float As[BM][BK + 1];
  __shared__ float Ws[BK][N];
  const int t = threadIdx.x;
  const int row0 = (int)blockIdx.x * BM;
  const int rg = t >> 4, cg = t & 15;
  const int r0 = rg * 4, c0 = cg * 4;
  float acc[4][4];
  #pragma unroll
  for (int i = 0; i < 4; ++i)
    #pragma unroll
    for (int j = 0; j < 4; ++j) acc[i][j] = 0.f;

  for (int kb = 0; kb < K; kb += BK) {
    #pragma unroll
    for (int u = 0; u < 2; ++u) {
      int id = t + u * 256;
      int ar = id >> 3, ac = (id & 7) * 4;
      float4 v = make_float4(0.f, 0.f, 0.f, 0.f);
      int grow = row0 + ar;
      if (grow < M) v = *reinterpret_cast<const float4*>(&A[(size_t)grow * K + kb + ac]);
      As[ar][ac] = v.x; As[ar][ac + 1] = v.y; As[ar][ac + 2] = v.z; As[ar][ac + 3] = v.w;
    }
    #pragma unroll
    for (int u = 0; u < 2; ++u) {
      int id = t + u * 256;
      int wr = id >> 4, wc = (id & 15) * 4;
      *reinterpret_cast<float4*>(&Ws[wr][wc]) =
          *reinterpret_cast<const float4*>(&W[(size_t)(kb + wr) * N + wc]);
    }
    __syncthreads();
    #pragma unroll
    for (int k = 0; k < BK; ++k) {
      float av[4] = {As[r0][k], As[r0 + 1][k], As[r0 + 2][k], As[r0 + 3][k]};
      float4 w0 = *reinterpret_cast<const float4*>(&Ws[k][c0]);
      #pragma unroll
      for (int i = 0; i < 4; ++i) {
        acc[i][0] += av[i] * w0.x; acc[i][1] += av[i] * w0.y;
        acc[i][2] += av[i] * w0.z; acc[i][3] += av[i] * w0.w;
      }
    }
    __syncthreads();
  }
  #pragma unroll
  for (int i = 0; i < 4; ++i) {
    int grow = row0 + r0 + i;
    if (grow >= M) continue;
    *reinterpret_cast<float4*>(&C[(size_t)grow * N + c0]) =
        make_float4(acc[i][0], acc[i][1], acc[i][2], acc[i][3]);
  }
}

// ---------------------------------------------------------------------------
// Score: p = efeat[e,:] . w̃ (16 lanes/edge), s_raw = lrelu(dsrc+ddst+p).
// No atomics.
// ---------------------------------------------------------------------------
__global__ __launch_bounds__(256)
void score_edge_k(const float* __restrict__ Ef, const float* __restrict__ wt,
                  const float* __restrict__ dsrc, const float* __restrict__ ddst,
                  const int* __restrict__ src, const int* __restrict__ dst,
                  float* __restrict__ s_out, int E) {
  int gid = (int)blockIdx.x * 256 + threadIdx.x;
  int e = gid >> 4;
  int l = gid & 15;
  if (e >= E) return;
  float4 ev = *reinterpret_cast<const float4*>(&Ef[(size_t)e * 64 + l * 4]);
  float4 av = *reinterpret_cast<const float4*>(&wt[l * 4]);
  float p = ev.x * av.x + ev.y * av.y + ev.z * av.z + ev.w * av.w;
  #pragma unroll
  for (int off = 1; off < 16; off <<= 1) p += __shfl_xor(p, off);
  if (l == 0) {
    float s = dsrc[src[e]] + ddst[dst[e]] + p;
    s_out[e] = LRELU(s);
  }
}

// ---------------------------------------------------------------------------
// CSR gather-sum of raw scores at dst (optionally two etypes into one sum).
// ---------------------------------------------------------------------------
__global__ __launch_bounds__(256)
void sum_csr_k(const int* __restrict__ offA, const int* __restrict__ eidA,
               const float* __restrict__ sA,
               const int* __restrict__ offB, const int* __restrict__ eidB,
               const float* __restrict__ sB,
               float* __restrict__ sum, int n) {
  int d = (int)blockIdx.x * 256 + threadIdx.x;
  if (d >= n) return;
  float s = 0.f;
  int b = offA[d], e = offA[d + 1];
  for (int j = b; j < e; ++j) s += sA[eidA[j]];
  if (offB) {
    b = offB[d]; e = offB[d + 1];
    for (int j = b; j < e; ++j) s += sB[eidB[j]];
  }
  sum[d] = s;
}

// ---------------------------------------------------------------------------
// Fused edge projection + update (NO scatter; new_e written once to d_out):
//   proj = Ef_tile @ We ;  new_e = (s_raw/sum_src[src]) * (g[dst,:] + proj)
// 128-edge tile, 256 threads, 8 rows x 4 cols per thread.
// A staged transposed + XOR-swizzled (conflict-free b128 LDS reads).
// ---------------------------------------------------------------------------
__global__ __launch_bounds__(256)
void edge_proj_upd_k(const float* __restrict__ Ef, const float* __restrict__ W,
                     const float* __restrict__ g, const float* __restrict__ s_raw,
                     const float* __restrict__ sum_src, const int* __restrict__ src,
                     const int* __restrict__ dst, float* __restrict__ e_out, int E) {
  constexpr int BM = 128, K = 64, N = 64;
  __shared__ float AsT[K][BM];   // [k][swizzled row]
  __shared__ float Ws[K][N];
  const int t = threadIdx.x;
  const int row0 = (int)blockIdx.x * BM;
  const int rg = t >> 4, cg = t & 15;
  const int r0 = rg * 8, c0 = cg * 4;

  // stage A transposed + swizzled: (row ar, k) -> AsT[k][((ar>>2)^((k>>2)&7))*4 + (ar&3)]
  #pragma unroll
  for (int u = 0; u < 8; ++u) {
    int id = t + u * 256;               // 0..2047
    int ar = id >> 4;                   // 0..127
    int ac = (id & 15) * 4;             // 0..60
    float4 v = make_float4(0.f, 0.f, 0.f, 0.f);
    int ge = row0 + ar;
    if (ge < E) v = *reinterpret_cast<const float4*>(&Ef[(size_t)ge * K + ac]);
    int glo = ar & 3, gr = ar >> 2;
    AsT[ac + 0][((gr ^ (((ac + 0) >> 2) & 7)) << 2) | glo] = v.x;
    AsT[ac + 1][((gr ^ (((ac + 1) >> 2) & 7)) << 2) | glo] = v.y;
    AsT[ac + 2][((gr ^ (((ac + 2) >> 2) & 7)) << 2) | glo] = v.z;
    AsT[ac + 3][((gr ^ (((ac + 3) >> 2) & 7)) << 2) | glo] = v.w;
  }
  #pragma unroll
  for (int u = 0; u < 4; ++u) {
    int id = t + u * 256;
    int wr = id >> 4, wc = (id & 15) * 4;
    *reinterpret_cast<float4*>(&Ws[wr][wc]) =
        *reinterpret_cast<const float4*>(&W[(size_t)wr * N + wc]);
  }
  __syncthreads();

  float acc[8][4];
  #pragma unroll
  for (int i = 0; i < 8; ++i)
    #pragma unroll
    for (int j = 0; j < 4; ++j) acc[i][j] = 0.f;

  const int gb = r0 >> 2;               // 2*rg
  for (int k4 = 0; k4 < 16; ++k4) {
    int s = k4 & 7;
    int ca = (gb ^ s) << 2;
    int cb = ((gb + 1) ^ s) << 2;
    #pragma unroll
    for (int j4 = 0; j4 < 4; ++j4) {
      int k = k4 * 4 + j4;
      float4 a0 = *reinterpret_cast<const float4*>(&AsT[k][ca]);
      float4 a1 = *reinterpret_cast<const float4*>(&AsT[k][cb]);
      float4 w  = *reinterpret_cast<const float4*>(&Ws[k][c0]);
      #pragma unroll
      for (int j = 0; j < 4; ++j) {
        float wj = (&w.x)[j];
        acc[0][j] += a0.x * wj; acc[1][j] += a0.y * wj;
        acc[2][j] += a0.z * wj; acc[3][j] += a0.w * wj;
        acc[4][j] += a1.x * wj; acc[5][j] += a1.y * wj;
        acc[6][j] += a1.z * wj; acc[7][j] += a1.w * wj;
      }
    }
  }

  #pragma unroll
  for (int i = 0; i < 8; ++i) {
    int e = row0 + r0 + i;
    if (e >= E) continue;
    int d = dst[e];
    float s = s_raw[e] / sum_src[src[e]];
    float4 gv = *reinterpret_cast<const float4*>(&g[(size_t)d * 64 + c0]);
    float4 v = make_float4(s * (gv.x + acc[i][0]), s * (gv.y + acc[i][1]),
                           s * (gv.z + acc[i][2]), s * (gv.w + acc[i][3]));
    *reinterpret_cast<float4*>(&e_out[(size_t)e * 64 + c0]) = v;
  }
}

// ---------------------------------------------------------------------------
// Furniture node update, aggregate gather-staged from e_out via CSR:
//   A[d,:] = [ sum_ff new_eff | sum_rf new_erf ]  (staged in LDS)
//   C = h + lrelu(A @ [Wnc_ff ; Wnc_rf])
// ---------------------------------------------------------------------------
__global__ __launch_bounds__(256)
void node_upd_f_k(const float* __restrict__ e_ff, const float* __restrict__ e_rf,
                  const int* __restrict__ off_ff, const int* __restrict__ eid_ff,
                  const int* __restrict__ off_rf, const int* __restrict__ eid_rf,
                  const float* __restrict__ W1, const float* __restrict__ W2,
                  const float* __restrict__ h, float* __restrict__ C, int M) {
  constexpr int BM = 64, K = 128, N = 128, BK = 32;
  __shared__ float As[BM][K + 1];
  __shared__ float Ws[BK][N];
  const int t = threadIdx.x;
  const int row0 = (int)blockIdx.x * BM;
  const int wv = t >> 6, l = t & 63;
  for (int r = wv; r < BM; r += 4) {
    int d = row0 + r;
    float a0 = 0.f, a1 = 0.f;
    if (d < M) {
      int b = off_ff[d], e2 = off_ff[d + 1];
      for (int j = b; j < e2; ++j) a0 += e_ff[(size_t)eid_ff[j] * 64 + l];
      b = off_rf[d]; e2 = off_rf[d + 1];
      for (int j = b; j < e2; ++j) a1 += e_rf[(size_t)eid_rf[j] * 64 + l];
    }
    As[r][l] = a0;
    As[r][l + 64] = a1;
  }
  const int rg = t >> 4, cg = t & 15;
  const int r0 = rg * 4, c0 = cg * 4;
  float acc[4][8];
  #pragma unroll
  for (int i = 0; i < 4; ++i)
    #pragma unroll
    for (int j = 0; j < 8; ++j) acc[i][j] = 0.f;

  for (int kb = 0; kb < K; kb += BK) {
    __syncthreads();
    #pragma unroll
    for (int u = 0; u < 4; ++u) {
      int id = t + u * 256;
      int wr = id >> 5, wc = (id & 31) * 4;
      int kr = kb + wr;
      const float* Wsrc = (kr >= 64) ? &W2[(size_t)(kr - 64) * N + wc]
                                     : &W1[(size_t)kr * N + wc];
      *reinterpret_cast<float4*>(&Ws[wr][wc]) = *reinterpret_cast<const float4*>(Wsrc);
    }
    __syncthreads();
    #pragma unroll
    for (int k = 0; k < BK; ++k) {
      int kk = kb + k;
      float av[4] = {As[r0][kk], As[r0 + 1][kk], As[r0 + 2][kk], As[r0 + 3][kk]};
      float4 w0 = *reinterpret_cast<const float4*>(&Ws[k][c0]);
      float4 w1 = *reinterpret_cast<const float4*>(&Ws[k][c0 + 64]);
      #pragma unroll
      for (int i = 0; i < 4; ++i) {
        acc[i][0] += av[i] * w0.x; acc[i][1] += av[i] * w0.y;
        acc[i][2] += av[i] * w0.z; acc[i][3] += av[i] * w0.w;
        acc[i][4] += av[i] * w1.x; acc[i][5] += av[i] * w1.y;
        acc[i][6] += av[i] * w1.z; acc[i][7] += av[i] * w1.w;
      }
    }
  }
  #pragma unroll
  for (int i = 0; i < 4; ++i) {
    int grow = row0 + r0 + i;
    if (grow >= M) continue;
    float4 h0 = *reinterpret_cast<const float4*>(&h[(size_t)grow * N + c0]);
    float4 h1 = *reinterpret_cast<const float4*>(&h[(size_t)grow * N + c0 + 64]);
    float4 o0 = make_float4(h0.x + LRELU(acc[i][0]), h0.y + LRELU(acc[i][1]),
                            h0.z + LRELU(acc[i][2]), h0.w + LRELU(acc[i][3]));
    float4 o1 = make_float4(h1.x + LRELU(acc[i][4]), h1.y + LRELU(acc[i][5]),
                            h1.z + LRELU(acc[i][6]), h1.w + LRELU(acc[i][7]));
    *reinterpret_cast<float4*>(&C[(size_t)grow * N + c0]) = o0;
    *reinterpret_cast<float4*>(&C[(size_t)grow * N + c0 + 64]) = o1;
  }
}

// ---------------------------------------------------------------------------
// Room node update: A[d,:] = sum_rr new_err (CSR gather), C = h + lrelu(A@W)
// ---------------------------------------------------------------------------
__global__ __launch_bounds__(256)
void node_upd_r_k(const float* __restrict__ e_rr,
                  const int* __restrict__ off_rr, const int* __restrict__ eid_rr,
                  const float* __restrict__ W1, const float* __restrict__ h,
                  float* __restrict__ C, int M) {
  constexpr int BM = 64, K = 64, N = 128, BK = 32;
  __shared__ float As[BM][K + 1];
  __shared__ float Ws[BK][N];
  const int t = threadIdx.x;
  const int row0 = (int)blockIdx.x * BM;
  const int wv = t >> 6, l = t & 63;
  for (int r = wv; r < BM; r += 4) {
    int d = row0 + r;
    float a0 = 0.f;
    if (d < M) {
      int b = off_rr[d], e2 = off_rr[d + 1];
      for (int j = b; j < e2; ++j) a0 += e_rr[(size_t)eid_rr[j] * 64 + l];
    }
    As[r][l] = a0;
  }
  const int rg = t >> 4, cg = t & 15;
  const int r0 = rg * 4, c0 = cg * 4;
  float acc[4][8];
  #pragma unroll
  for (int i = 0; i < 4; ++i)
    #pragma unroll
    for (int j = 0; j < 8; ++j) acc[i][j] = 0.f;

  for (int kb = 0; kb < K; kb += BK) {
    __syncthreads();
    #pragma unroll
    for (int u = 0; u < 4; ++u) {
      int id = t + u * 256;
      int wr = id >> 5, wc = (id & 31) * 4;
      int kr = kb + wr;
      *reinterpret_cast<float4*>(&Ws[wr][wc]) =
          *reinterpret_cast<const float4*>(&W1[(size_t)kr * N + wc]);
    }
    __syncthreads();
    #pragma unroll
    for (int k = 0; k < BK; ++k) {
      int kk = kb + k;
      float av[4] = {As[r0][kk], As[r0 + 1][kk], As[r0 + 2][kk], As[r0 + 3][kk]};
      float4 w0 = *reinterpret_cast<const float4*>(&Ws[k][c0]);
      float4 w1 = *reinterpret_cast<const float4*>(&Ws[k][c0 + 64]);
      #pragma unroll
      for (int i = 0; i < 4; ++i) {
        acc[i][0] += av[i] * w0.x; acc[i][1] += av[i] * w0.y;
        acc[i][2] += av[i] * w0.z; acc[i][3] += av[i] * w0.w;
        acc[i][4] += av[i] * w1.x; acc[i][5] += av[i] * w1.y;
        acc[i][6] += av[i] * w1.z; acc[i][7] += av[i] * w1.w;
      }
    }
  }
  #pragma unroll
  for (int i = 0; i < 4; ++i) {
    int grow = row0 + r0 + i;
    if (grow >= M) continue;
    float4 h0 = *reinterpret_cast<const float4*>(&h[(size_t)grow * N + c0]);
    float4 h1 = *reinterpret_cast<const float4*>(&h[(size_t)grow * N + c0 + 64]);
    float4 o0 = make_float4(h0.x + LRELU(acc[i][0]), h0.y + LRELU(acc[i][1]),
                            h0.z + LRELU(acc[i][2]), h0.w + LRELU(acc[i][3]));
    float4 o1 = make_float4(h1.x + LRELU(acc[i][4]), h1.y + LRELU(acc[i][5]),
                            h1.z + LRELU(acc[i][6]), h1.w + LRELU(acc[i][7]));
    *reinterpret_cast<float4*>(&C[(size_t)grow * N + c0]) = o0;
    *reinterpret_cast<float4*>(&C[(size_t)grow * N + c0 + 64]) = o1;
  }
}

// ---------------------------------------------------------------------------
extern "C" void kernel_launch(void* const* d_in, const int* in_sizes, int n_in,
                              void* d_out, int out_size, void* d_ws, size_t ws_size,
                              hipStream_t stream) {
  const float* f_feat   = (const float*)d_in[0];
  const float* r_feat   = (const float*)d_in[1];
  const float* ff_efeat = (const float*)d_in[2];
  const float* rr_efeat = (const float*)d_in[3];
  const float* rf_efeat = (const float*)d_in[4];
  const float* Wf     = (const float*)d_in[5];
  const float* Wr     = (const float*)d_in[6];
  const float* We_ff  = (const float*)d_in[7];
  const float* We_rr  = (const float*)d_in[8];
  const float* We_rf  = (const float*)d_in[9];
  const float* a_ff   = (const float*)d_in[10];
  const float* a_rr   = (const float*)d_in[11];
  const float* a_rf   = (const float*)d_in[12];
  const float* Wec_ff = (const float*)d_in[13];
  const float* Wec_rr = (const float*)d_in[14];
  const float* Wec_rf = (const float*)d_in[15];
  const float* Wnc_ff = (const float*)d_in[16];
  const float* Wnc_rr = (const float*)d_in[17];
  const float* Wnc_rf = (const float*)d_in[18];
  const int* ff_src = (const int*)d_in[19];
  const int* ff_dst = (const int*)d_in[20];
  const int* rr_src = (const int*)d_in[21];
  const int* rr_dst = (const int*)d_in[22];
  const int* rf_src = (const int*)d_in[23];
  const int* rf_dst = (const int*)d_in[24];

  float* out = (float*)d_out;
  float* ws  = (float*)d_ws;
  int*   wsI = (int*)(ws + WS_INT);

  float* hf     = ws + WS_HF;
  float* hr     = ws + WS_HR;
  float* gfc_ff = ws + WS_GFC_FF;
  float* gfc_rf = ws + WS_GFC_RF;
  float* grc_rr = ws + WS_GRC_RR;
  float* wt     = ws + WS_WT;
  float* sum_f  = ws + WS_SUMF;
  float* sum_r  = ws + WS_SUMR;

  int* cur_ff = wsI + I_CUR_FF;
  int* cur_rf = wsI + I_CUR_RF;
  int* cur_rr = wsI + I_CUR_RR;
  int* off_ff = wsI + I_OFF_FF;
  int* off_rf = wsI + I_OFF_RF;
  int* off_rr = wsI + I_OFF_RR;
  int* eid_ff = wsI + I_EID_FF;
  int* eid_rf = wsI + I_EID_RF;
  int* eid_rr = wsI + I_EID_RR;

  float* out_eff = out + OFF_EFF;
  float* out_err = out + OFF_ERR;
  float* out_erf = out + OFF_ERF;

  // zero CSR histograms
  hipMemsetAsync(wsI, 0, I_ZERO_CNT * sizeof(int), stream);

  // w̃ = We @ a_e (tiny)
  wtilde_k<<<1, 192, 0, stream>>>(We_ff, We_rr, We_rf, a_ff, a_rr, a_rf, wt);

  // CSR build (by dst) for the three edge types
  hist_k<<<(E_FF + 255) / 256, 256, 0, stream>>>(ff_dst, cur_ff, E_FF);
  hist_k<<<(E_RF + 255) / 256, 256, 0, stream>>>(rf_dst, cur_rf, E_RF);
  hist_k<<<(E_RR + 255) / 256, 256, 0, stream>>>(rr_dst, cur_rr, E_RR);
  scan_k<<<1, 1024, 0, stream>>>(cur_ff, off_ff, N_F);
  scan_k<<<1, 1024, 0, stream>>>(cur_rf, off_rf, N_F);
  scan_k<<<1, 1024, 0, stream>>>(cur_rr, off_rr, N_R);
  fill_k<<<(E_FF + 255) / 256, 256, 0, stream>>>(ff_dst, cur_ff, eid_ff, E_FF);
  fill_k<<<(E_RF + 255) / 256, 256, 0, stream>>>(rf_dst, cur_rf, eid_rf, E_RF);
  fill_k<<<(E_RR + 255) / 256, 256, 0, stream>>>(rr_dst, cur_rr, eid_rr, E_RR);

  // node projections fused with the 3 per-node attention dots
  gemm_dot3_128<<<(N_F + 63) / 64, 256, 0, stream>>>(
      f_feat, Wf, a_ff, a_ff + 128, a_rf + 128, hf,
      ws + WS_DF_FFS, ws + WS_DF_FFD, ws + WS_DF_RFD, N_F);
  gemm_dot3_128<<<(N_R + 63) / 64, 256, 0, stream>>>(
      r_feat, Wr, a_rr, a_rr + 128, a_rf, hr,
      ws + WS_DR_RRS, ws + WS_DR_RRD, ws + WS_DR_RFS, N_R);

  // edge-converter projections
  gemm_128x64<<<(N_F + 63) / 64, 256, 0, stream>>>(hf, Wec_ff, gfc_ff, N_F);
  gemm_128x64<<<(N_F + 63) / 64, 256, 0, stream>>>(hf, Wec_rf, gfc_rf, N_F);
  gemm_128x64<<<(N_R + 63) / 64, 256, 0, stream>>>(hr, Wec_rr, grc_rr, N_R);

  // scores from RAW efeat (projection folded into w̃), no atomics
  score_edge_k<<<(E_FF * 16 + 255) / 256, 256, 0, stream>>>(
      ff_efeat, wt, ws + WS_DF_FFS, ws + WS_DF_FFD, ff_src, ff_dst,
      ws + WS_SFF, E_FF);
  score_edge_k<<<(E_RR * 16 + 255) / 256, 256, 0, stream>>>(
      rr_efeat, wt + 64, ws + WS_DR_RRS, ws + WS_DR_RRD, rr_src, rr_dst,
      ws + WS_SRR, E_RR);
  score_edge_k<<<(E_RF * 16 + 255) / 256, 256, 0, stream>>>(
      rf_efeat, wt + 128, ws + WS_DR_RFS, ws + WS_DF_RFD, rf_src, rf_dst,
      ws + WS_SRF, E_RF);

  // dst score sums via CSR gather (no atomics)
  sum_csr_k<<<(N_F + 255) / 256, 256, 0, stream>>>(
      off_ff, eid_ff, ws + WS_SFF, off_rf, eid_rf, ws + WS_SRF, sum_f, N_F);
  sum_csr_k<<<(N_R + 255) / 256, 256, 0, stream>>>(
      off_rr, eid_rr, ws + WS_SRR, nullptr, nullptr, nullptr, sum_r, N_R);

  // fused projection + edge update (write-once, no scatter)
  edge_proj_upd_k<<<(E_FF + 127) / 128, 256, 0, stream>>>(
      ff_efeat, We_ff, gfc_ff, ws + WS_SFF, sum_f, ff_src, ff_dst, out_eff, E_FF);
  edge_proj_upd_k<<<(E_RR + 127) / 128, 256, 0, stream>>>(
      rr_efeat, We_rr, grc_rr, ws + WS_SRR, sum_r, rr_src, rr_dst, out_err, E_RR);
  edge_proj_upd_k<<<(E_RF + 127) / 128, 256, 0, stream>>>(
      rf_efeat, We_rf, gfc_rf, ws + WS_SRF, sum_r, rf_src, rf_dst, out_erf, E_RF);

  // node updates with CSR gather-staged aggregates (no agg materialization)
  node_upd_f_k<<<(N_F + 63) / 64, 256, 0, stream>>>(
      out_eff, out_erf, off_ff, eid_ff, off_rf, eid_rf,
      Wnc_ff, Wnc_rf, hf, out + OFF_NF, N_F);
  node_upd_r_k<<<(N_R + 63) / 64, 256, 0, stream>>>(
      out_err, off_rr, eid_rr, Wnc_rr, hr, out + OFF_NR, N_R);
}

// Round 7
// 1389.345 us; speedup vs baseline: 1.2562x; 1.2562x over previous
//
#include <hip/hip_runtime.h>
#include <hip/hip_bf16.h>

#define LRELU(x) ((x) >= 0.f ? (x) : 0.01f * (x))

// ---------------------------------------------------------------------------
// Problem constants (match reference setup_inputs)
// ---------------------------------------------------------------------------
static constexpr int N_F = 50000, N_R = 25000;
static constexpr int E_FF = 400000, E_RR = 200000, E_RF = 400000;

// d_out layout (floats)
static constexpr size_t OFF_NF  = 0;                          // new_f  [50000,128]
static constexpr size_t OFF_NR  = OFF_NF + (size_t)N_F * 128; // new_r  [25000,128]
static constexpr size_t OFF_EFF = OFF_NR + (size_t)N_R * 128; // new_eff[400000,64]
static constexpr size_t OFF_ERR = OFF_EFF + (size_t)E_FF * 64;// new_err[200000,64]
static constexpr size_t OFF_ERF = OFF_ERR + (size_t)E_RR * 64;// new_erf[400000,64]

// workspace layout (floats)
static constexpr size_t WS_HF      = 0;                          // [50000,128]
static constexpr size_t WS_HR      = WS_HF + (size_t)N_F * 128;  // [25000,128]
static constexpr size_t WS_GFC_FF  = WS_HR + (size_t)N_R * 128;  // [50000,64]
static constexpr size_t WS_GFC_RF  = WS_GFC_FF + (size_t)N_F * 64;
static constexpr size_t WS_GRC_RR  = WS_GFC_RF + (size_t)N_F * 64; // [25000,64]
static constexpr size_t WS_DF_FFS  = WS_GRC_RR + (size_t)N_R * 64; // [50000]
static constexpr size_t WS_DF_FFD  = WS_DF_FFS + N_F;
static constexpr size_t WS_DF_RFD  = WS_DF_FFD + N_F;
static constexpr size_t WS_DR_RRS  = WS_DF_RFD + N_F;              // [25000]
static constexpr size_t WS_DR_RRD  = WS_DR_RRS + N_R;
static constexpr size_t WS_DR_RFS  = WS_DR_RRD + N_R;
static constexpr size_t WS_SFF     = WS_DR_RFS + N_R;              // [400000] raw lrelu scores
static constexpr size_t WS_SRR     = WS_SFF + E_FF;
static constexpr size_t WS_SRF     = WS_SRR + E_RR;
static constexpr size_t WS_WT      = WS_SRF + E_RF;                // [192]
static constexpr size_t WS_SUMF    = WS_WT + 192;                  // [50000]
static constexpr size_t WS_SUMR    = WS_SUMF + N_F;                // [25000]
static constexpr size_t WS_AGGF    = WS_SUMR + N_R;                // [50000,128] (ff 0..63, rf 64..127)
static constexpr size_t WS_AGGR    = WS_AGGF + (size_t)N_F * 128;  // [25000,64]
static constexpr size_t WS_INT     = WS_AGGR + (size_t)N_R * 64;   // int region below

// int region offsets (in ints, relative to WS_INT)
static constexpr size_t I_CUR_FF = 0;                 // [50000]  (zeroed; hist cnt -> fill cursor)
static constexpr size_t I_CUR_RF = I_CUR_FF + N_F;    // [50000]
static constexpr size_t I_CUR_RR = I_CUR_RF + N_F;    // [25000]
static constexpr size_t I_ZERO_CNT = I_CUR_RR + N_R;  // 125000 ints zeroed
static constexpr size_t I_OFF_FF = I_ZERO_CNT;        // [50001]
static constexpr size_t I_OFF_RF = I_OFF_FF + N_F + 1;// [50001]
static constexpr size_t I_OFF_RR = I_OFF_RF + N_F + 1;// [25001]
static constexpr size_t I_EID_FF = I_OFF_RR + N_R + 1;// [400000]
static constexpr size_t I_EID_RF = I_EID_FF + E_FF;   // [400000]
static constexpr size_t I_EID_RR = I_EID_RF + E_RF;   // [200000]

// ---------------------------------------------------------------------------
// Tiny: w̃ = We @ a_e for the three edge types.
// ---------------------------------------------------------------------------
__global__ void wtilde_k(const float* __restrict__ We_ff, const float* __restrict__ We_rr,
                         const float* __restrict__ We_rf, const float* __restrict__ a_ff,
                         const float* __restrict__ a_rr, const float* __restrict__ a_rf,
                         float* __restrict__ wt) {
  int t = threadIdx.x;
  if (t >= 192) return;
  int grp = t >> 6, k = t & 63;
  const float* W = (grp == 0) ? We_ff : (grp == 1) ? We_rr : We_rf;
  const float* a = (grp == 0) ? a_ff + 256 : (grp == 1) ? a_rr + 256 : a_rf + 256;
  float s = 0.f;
  #pragma unroll 8
  for (int j = 0; j < 64; ++j) s += W[k * 64 + j] * a[j];
  wt[t] = s;
}

// ---------------------------------------------------------------------------
// CSR build: histogram -> exclusive scan (single block) -> fill
// ---------------------------------------------------------------------------
__global__ __launch_bounds__(256)
void hist_k(const int* __restrict__ dst, int* __restrict__ cnt, int E) {
  int e = (int)blockIdx.x * 256 + threadIdx.x;
  if (e < E) atomicAdd(&cnt[dst[e]], 1);
}

__global__ __launch_bounds__(1024)
void scan_k(int* __restrict__ cnt /*in: counts, out: cursor=start*/,
            int* __restrict__ off /*[n+1]*/, int n) {
  __shared__ int ls[1024];
  int t = threadIdx.x;
  int chunk = (n + 1023) / 1024;
  int beg = t * chunk;
  int end = beg + chunk < n ? beg + chunk : n;
  int s = 0;
  for (int i = beg; i < end; ++i) s += cnt[i];
  ls[t] = s;
  __syncthreads();
  for (int d = 1; d < 1024; d <<= 1) {
    int v = (t >= d) ? ls[t - d] : 0;
    __syncthreads();
    ls[t] += v;
    __syncthreads();
  }
  int run = (t == 0) ? 0 : ls[t - 1];
  for (int i = beg; i < end; ++i) {
    int c = cnt[i];
    off[i] = run;
    cnt[i] = run;   // cursor for fill
    run += c;
  }
  if (t == 1023) off[n] = ls[1023];
}

__global__ __launch_bounds__(256)
void fill_k(const int* __restrict__ dst, int* __restrict__ cur,
            int* __restrict__ eid, int E) {
  int e = (int)blockIdx.x * 256 + threadIdx.x;
  if (e < E) {
    int pos = atomicAdd(&cur[dst[e]], 1);
    eid[pos] = e;
  }
}

// ---------------------------------------------------------------------------
// Node projection GEMM fused with 3 attention dots:
//   C[M,128] = A[M,128] @ W[128,128];  d_i[m] = C[m,:] . a_i
// ---------------------------------------------------------------------------
__global__ __launch_bounds__(256)
void gemm_dot3_128(const float* __restrict__ A, const float* __restrict__ W,
                   const float* __restrict__ a0, const float* __restrict__ a1,
                   const float* __restrict__ a2, float* __restrict__ C,
                   float* __restrict__ d0, float* __restrict__ d1,
                   float* __restrict__ d2, int M) {
  constexpr int K = 128, N = 128, BM = 64, BK = 32;
  __shared__ float As[BM][BK + 1];
  __shared__ float Ws[BK][N];
  const int t = threadIdx.x;
  const int row0 = (int)blockIdx.x * BM;
  const int rg = t >> 4, cg = t & 15;
  const int r0 = rg * 4, c0 = cg * 4;

  float acc[4][8];
  #pragma unroll
  for (int i = 0; i < 4; ++i)
    #pragma unroll
    for (int j = 0; j < 8; ++j) acc[i][j] = 0.f;

  for (int kb = 0; kb < K; kb += BK) {
    #pragma unroll
    for (int u = 0; u < 2; ++u) {
      int id = t + u * 256;
      int ar = id >> 3, ac = (id & 7) * 4;
      float4 v = make_float4(0.f, 0.f, 0.f, 0.f);
      int grow = row0 + ar;
      if (grow < M) v = *reinterpret_cast<const float4*>(&A[(size_t)grow * K + kb + ac]);
      As[ar][ac] = v.x; As[ar][ac + 1] = v.y; As[ar][ac + 2] = v.z; As[ar][ac + 3] = v.w;
    }
    #pragma unroll
    for (int u = 0; u < 4; ++u) {
      int id = t + u * 256;
      int wr = id >> 5, wc = (id & 31) * 4;
      *reinterpret_cast<float4*>(&Ws[wr][wc]) =
          *reinterpret_cast<const float4*>(&W[(size_t)(kb + wr) * N + wc]);
    }
    __syncthreads();
    #pragma unroll
    for (int k = 0; k < BK; ++k) {
      float av[4] = {As[r0][k], As[r0 + 1][k], As[r0 + 2][k], As[r0 + 3][k]};
      float4 w0 = *reinterpret_cast<const float4*>(&Ws[k][c0]);
      float4 w1 = *reinterpret_cast<const float4*>(&Ws[k][c0 + 64]);
      #pragma unroll
      for (int i = 0; i < 4; ++i) {
        acc[i][0] += av[i] * w0.x; acc[i][1] += av[i] * w0.y;
        acc[i][2] += av[i] * w0.z; acc[i][3] += av[i] * w0.w;
        acc[i][4] += av[i] * w1.x; acc[i][5] += av[i] * w1.y;
        acc[i][6] += av[i] * w1.z; acc[i][7] += av[i] * w1.w;
      }
    }
    __syncthreads();
  }
  float4 a0l = *reinterpret_cast<const float4*>(&a0[c0]);
  float4 a0h = *reinterpret_cast<const float4*>(&a0[c0 + 64]);
  float4 a1l = *reinterpret_cast<const float4*>(&a1[c0]);
  float4 a1h = *reinterpret_cast<const float4*>(&a1[c0 + 64]);
  float4 a2l = *reinterpret_cast<const float4*>(&a2[c0]);
  float4 a2h = *reinterpret_cast<const float4*>(&a2[c0 + 64]);
  #pragma unroll
  for (int i = 0; i < 4; ++i) {
    int grow = row0 + r0 + i;
    if (grow < M) {
      *reinterpret_cast<float4*>(&C[(size_t)grow * N + c0]) =
          make_float4(acc[i][0], acc[i][1], acc[i][2], acc[i][3]);
      *reinterpret_cast<float4*>(&C[(size_t)grow * N + c0 + 64]) =
          make_float4(acc[i][4], acc[i][5], acc[i][6], acc[i][7]);
    }
    float p0 = acc[i][0] * a0l.x + acc[i][1] * a0l.y + acc[i][2] * a0l.z + acc[i][3] * a0l.w
             + acc[i][4] * a0h.x + acc[i][5] * a0h.y + acc[i][6] * a0h.z + acc[i][7] * a0h.w;
    float p1 = acc[i][0] * a1l.x + acc[i][1] * a1l.y + acc[i][2] * a1l.z + acc[i][3] * a1l.w
             + acc[i][4] * a1h.x + acc[i][5] * a1h.y + acc[i][6] * a1h.z + acc[i][7] * a1h.w;
    float p2 = acc[i][0] * a2l.x + acc[i][1] * a2l.y + acc[i][2] * a2l.z + acc[i][3] * a2l.w
             + acc[i][4] * a2h.x + acc[i][5] * a2h.y + acc[i][6] * a2h.z + acc[i][7] * a2h.w;
    #pragma unroll
    for (int off = 1; off < 16; off <<= 1) {
      p0 += __shfl_xor(p0, off);
      p1 += __shfl_xor(p1, off);
      p2 += __shfl_xor(p2, off);
    }
    if (cg == 0 && grow < M) { d0[grow] = p0; d1[grow] = p1; d2[grow] = p2; }
  }
}

// ---------------------------------------------------------------------------
// Plain tiled GEMM (edge-converter projections): C[M,64] = A[M,128] @ W[128,64]
// ---------------------------------------------------------------------------
__global__ __launch_bounds__(256)
void gemm_128x64(const float* __restrict__ A, const float* __restrict__ W,
                 float* __restrict__ C, int M) {
  constexpr int K = 128, N = 64, BM = 64, BK = 32;
  __shared__ float As[BM][BK + 1];
  __shared__ float Ws[BK][N];
  const int t = threadIdx.x;
  const int row0 = (int)blockIdx.x * BM;
  const int rg = t >> 4, cg = t & 15;
  const int r0 = rg * 4, c0 = cg * 4;
  float acc[4][4];
  #pragma unroll
  for (int i = 0; i < 4; ++i)
    #pragma unroll
    for (int j = 0; j < 4; ++j) acc[i][j] = 0.f;

  for (int kb = 0; kb < K; kb += BK) {
    #pragma unroll
    for (int u = 0; u < 2; ++u) {
      int id = t + u * 256;
      int ar = id >> 3, ac = (id & 7) * 4;
      float4 v = make_float4(0.f, 0.f, 0.f, 0.f);
      int grow = row0 + ar;
      if (grow < M) v = *reinterpret_cast<const float4*>(&A[(size_t)grow * K + kb + ac]);
      As[ar][ac] = v.x; As[ar][ac + 1] = v.y; As[ar][ac + 2] = v.z; As[ar][ac + 3] = v.w;
    }
    #pragma unroll
    for (int u = 0; u < 2; ++u) {
      int id = t + u * 256;
      int wr = id >> 4, wc = (id & 15) * 4;
      *reinterpret_cast<float4*>(&Ws[wr][wc]) =
          *reinterpret_cast<const float4*>(&W[(size_t)(kb + wr) * N + wc]);
    }
    __syncthreads();
    #pragma unroll
    for (int k = 0; k < BK; ++k) {
      float av[4] = {As[r0][k], As[r0 + 1][k], As[r0 + 2][k], As[r0 + 3][k]};
      float4 w0 = *reinterpret_cast<const float4*>(&Ws[k][c0]);
      #pragma unroll
      for (int i = 0; i < 4; ++i) {
        acc[i][0] += av[i] * w0.x; acc[i][1] += av[i] * w0.y;
        acc[i][2] += av[i] * w0.z; acc[i][3] += av[i] * w0.w;
      }
    }
    __syncthreads();
  }
  #pragma unroll
  for (int i = 0; i < 4; ++i) {
    int grow = row0 + r0 + i;
    if (grow >= M) continue;
    *reinterpret_cast<float4*>(&C[(size_t)grow * N + c0]) =
        make_float4(acc[i][0], acc[i][1], acc[i][2], acc[i][3]);
  }
}

// ---------------------------------------------------------------------------
// Score: p = efeat[e,:] . w̃ (16 lanes/edge), s_raw = lrelu(dsrc+ddst+p).
// No atomics.
// ---------------------------------------------------------------------------
__global__ __launch_bounds__(256)
void score_edge_k(const float* __restrict__ Ef, const float* __restrict__ wt,
                  const float* __restrict__ dsrc, const float* __restrict__ ddst,
                  const int* __restrict__ src, const int* __restrict__ dst,
                  float* __restrict__ s_out, int E) {
  int gid = (int)blockIdx.x * 256 + threadIdx.x;
  int e = gid >> 4;
  int l = gid & 15;
  if (e >= E) return;
  float4 ev = *reinterpret_cast<const float4*>(&Ef[(size_t)e * 64 + l * 4]);
  float4 av = *reinterpret_cast<const float4*>(&wt[l * 4]);
  float p = ev.x * av.x + ev.y * av.y + ev.z * av.z + ev.w * av.w;
  #pragma unroll
  for (int off = 1; off < 16; off <<= 1) p += __shfl_xor(p, off);
  if (l == 0) {
    float s = dsrc[src[e]] + ddst[dst[e]] + p;
    s_out[e] = LRELU(s);
  }
}

// ---------------------------------------------------------------------------
// CSR gather-sum of raw scores at dst (optionally two etypes into one sum).
// ---------------------------------------------------------------------------
__global__ __launch_bounds__(256)
void sum_csr_k(const int* __restrict__ offA, const int* __restrict__ eidA,
               const float* __restrict__ sA,
               const int* __restrict__ offB, const int* __restrict__ eidB,
               const float* __restrict__ sB,
               float* __restrict__ sum, int n) {
  int d = (int)blockIdx.x * 256 + threadIdx.x;
  if (d >= n) return;
  float s = 0.f;
  int b = offA[d], e = offA[d + 1];
  for (int j = b; j < e; ++j) s += sA[eidA[j]];
  if (offB) {
    b = offB[d]; e = offB[d + 1];
    for (int j = b; j < e; ++j) s += sB[eidB[j]];
  }
  sum[d] = s;
}

// ---------------------------------------------------------------------------
// Fused edge projection + update (NO scatter; new_e written once to d_out):
//   proj = Ef_tile @ We ;  new_e = (s_raw/sum_src[src]) * (g[dst,:] + proj)
// 128-edge tile, 256 threads, 8 rows x 4 cols per thread.
// A staged transposed + XOR-swizzled (conflict-free b128 LDS reads).
// ---------------------------------------------------------------------------
__global__ __launch_bounds__(256)
void edge_proj_upd_k(const float* __restrict__ Ef, const float* __restrict__ W,
                     const float* __restrict__ g, const float* __restrict__ s_raw,
                     const float* __restrict__ sum_src, const int* __restrict__ src,
                     const int* __restrict__ dst, float* __restrict__ e_out, int E) {
  constexpr int BM = 128, K = 64, N = 64;
  __shared__ float AsT[K][BM];   // [k][swizzled row]
  __shared__ float Ws[K][N];
  const int t = threadIdx.x;
  const int row0 = (int)blockIdx.x * BM;
  const int rg = t >> 4, cg = t & 15;
  const int r0 = rg * 8, c0 = cg * 4;

  // stage A transposed + swizzled: (row ar, k) -> AsT[k][((ar>>2)^((k>>2)&7))*4 + (ar&3)]
  #pragma unroll
  for (int u = 0; u < 8; ++u) {
    int id = t + u * 256;               // 0..2047
    int ar = id >> 4;                   // 0..127
    int ac = (id & 15) * 4;             // 0..60
    float4 v = make_float4(0.f, 0.f, 0.f, 0.f);
    int ge = row0 + ar;
    if (ge < E) v = *reinterpret_cast<const float4*>(&Ef[(size_t)ge * K + ac]);
    int glo = ar & 3, gr = ar >> 2;
    AsT[ac + 0][((gr ^ (((ac + 0) >> 2) & 7)) << 2) | glo] = v.x;
    AsT[ac + 1][((gr ^ (((ac + 1) >> 2) & 7)) << 2) | glo] = v.y;
    AsT[ac + 2][((gr ^ (((ac + 2) >> 2) & 7)) << 2) | glo] = v.z;
    AsT[ac + 3][((gr ^ (((ac + 3) >> 2) & 7)) << 2) | glo] = v.w;
  }
  #pragma unroll
  for (int u = 0; u < 4; ++u) {
    int id = t + u * 256;
    int wr = id >> 4, wc = (id & 15) * 4;
    *reinterpret_cast<float4*>(&Ws[wr][wc]) =
        *reinterpret_cast<const float4*>(&W[(size_t)wr * N + wc]);
  }
  __syncthreads();

  float acc[8][4];
  #pragma unroll
  for (int i = 0; i < 8; ++i)
    #pragma unroll
    for (int j = 0; j < 4; ++j) acc[i][j] = 0.f;

  const int gb = r0 >> 2;               // 2*rg
  for (int k4 = 0; k4 < 16; ++k4) {
    int s = k4 & 7;
    int ca = (gb ^ s) << 2;
    int cb = ((gb + 1) ^ s) << 2;
    #pragma unroll
    for (int j4 = 0; j4 < 4; ++j4) {
      int k = k4 * 4 + j4;
      float4 a0 = *reinterpret_cast<const float4*>(&AsT[k][ca]);
      float4 a1 = *reinterpret_cast<const float4*>(&AsT[k][cb]);
      float4 w  = *reinterpret_cast<const float4*>(&Ws[k][c0]);
      #pragma unroll
      for (int j = 0; j < 4; ++j) {
        float wj = (&w.x)[j];
        acc[0][j] += a0.x * wj; acc[1][j] += a0.y * wj;
        acc[2][j] += a0.z * wj; acc[3][j] += a0.w * wj;
        acc[4][j] += a1.x * wj; acc[5][j] += a1.y * wj;
        acc[6][j] += a1.z * wj; acc[7][j] += a1.w * wj;
      }
    }
  }

  #pragma unroll
  for (int i = 0; i < 8; ++i) {
    int e = row0 + r0 + i;
    if (e >= E) continue;
    int d = dst[e];
    float s = s_raw[e] / sum_src[src[e]];
    float4 gv = *reinterpret_cast<const float4*>(&g[(size_t)d * 64 + c0]);
    float4 v = make_float4(s * (gv.x + acc[i][0]), s * (gv.y + acc[i][1]),
                           s * (gv.z + acc[i][2]), s * (gv.w + acc[i][3]));
    *reinterpret_cast<float4*>(&e_out[(size_t)e * 64 + c0]) = v;
  }
}

// ---------------------------------------------------------------------------
// Dedicated CSR aggregation, ONE WAVE PER DST NODE (lane = column):
//   agg[d, 0:64]   = sum over ff-edges of e_ff[eid, lane]
//   agg[d, 64:128] = sum over rf-edges of e_rf[eid, lane]
// Coalesced 256B row reads, no LDS, high occupancy -> latency-hiding by TLP.
// ---------------------------------------------------------------------------
__global__ __launch_bounds__(256)
void agg_f_k(const float* __restrict__ e_ff, const float* __restrict__ e_rf,
             const int* __restrict__ off_ff, const int* __restrict__ eid_ff,
             const int* __restrict__ off_rf, const int* __restrict__ eid_rf,
             float* __restrict__ agg, int M) {
  int node = ((int)blockIdx.x * 256 + threadIdx.x) >> 6;
  int l = threadIdx.x & 63;
  if (node >= M) return;
  float a0 = 0.f, a1 = 0.f;
  int b = off_ff[node], e = off_ff[node + 1];
  for (int j = b; j < e; ++j) a0 += e_ff[(size_t)eid_ff[j] * 64 + l];
  b = off_rf[node]; e = off_rf[node + 1];
  for (int j = b; j < e; ++j) a1 += e_rf[(size_t)eid_rf[j] * 64 + l];
  agg[(size_t)node * 128 + l] = a0;
  agg[(size_t)node * 128 + 64 + l] = a1;
}

__global__ __launch_bounds__(256)
void agg_r_k(const float* __restrict__ e_rr,
             const int* __restrict__ off_rr, const int* __restrict__ eid_rr,
             float* __restrict__ agg, int M) {
  int node = ((int)blockIdx.x * 256 + threadIdx.x) >> 6;
  int l = threadIdx.x & 63;
  if (node >= M) return;
  float a0 = 0.f;
  int b = off_rr[node], e = off_rr[node + 1];
  for (int j = b; j < e; ++j) a0 += e_rr[(size_t)eid_rr[j] * 64 + l];
  agg[(size_t)node * 64 + l] = a0;
}

// ---------------------------------------------------------------------------
// Node update (dense A): C[M,128] = h + lrelu(A[M,K] @ Wcat[K,128]);
// W rows >=64 come from W2 when K==128.
// ---------------------------------------------------------------------------
template<int K>
__global__ __launch_bounds__(256)
void node_update_k(const float* __restrict__ A, const float* __restrict__ W1,
                   const float* __restrict__ W2, const float* __restrict__ h,
                   float* __restrict__ C, int M) {
  constexpr int N = 128, BM = 64, BK = 32;
  __shared__ float As[BM][BK + 1];
  __shared__ float Ws[BK][N];
  const int t = threadIdx.x;
  const int row0 = (int)blockIdx.x * BM;
  const int rg = t >> 4, cg = t & 15;
  const int r0 = rg * 4, c0 = cg * 4;
  float acc[4][8];
  #pragma unroll
  for (int i = 0; i < 4; ++i)
    #pragma unroll
    for (int j = 0; j < 8; ++j) acc[i][j] = 0.f;

  for (int kb = 0; kb < K; kb += BK) {
    #pragma unroll
    for (int u = 0; u < 2; ++u) {
      int id = t + u * 256;
      int ar = id >> 3, ac = (id & 7) * 4;
      float4 v = make_float4(0.f, 0.f, 0.f, 0.f);
      int grow = row0 + ar;
      if (grow < M) v = *reinterpret_cast<const float4*>(&A[(size_t)grow * K + kb + ac]);
      As[ar][ac] = v.x; As[ar][ac + 1] = v.y; As[ar][ac + 2] = v.z; As[ar][ac + 3] = v.w;
    }
    #pragma unroll
    for (int u = 0; u < 4; ++u) {
      int id = t + u * 256;
      int wr = id >> 5, wc = (id & 31) * 4;
      int kr = kb + wr;
      const float* Wsrc = (K == 128 && kr >= 64) ? &W2[(size_t)(kr - 64) * N + wc]
                                                 : &W1[(size_t)kr * N + wc];
      *reinterpret_cast<float4*>(&Ws[wr][wc]) = *reinterpret_cast<const float4*>(Wsrc);
    }
    __syncthreads();
    #pragma unroll
    for (int k = 0; k < BK; ++k) {
      float av[4] = {As[r0][k], As[r0 + 1][k], As[r0 + 2][k], As[r0 + 3][k]};
      float4 w0 = *reinterpret_cast<const float4*>(&Ws[k][c0]);
      float4 w1 = *reinterpret_cast<const float4*>(&Ws[k][c0 + 64]);
      #pragma unroll
      for (int i = 0; i < 4; ++i) {
        acc[i][0] += av[i] * w0.x; acc[i][1] += av[i] * w0.y;
        acc[i][2] += av[i] * w0.z; acc[i][3] += av[i] * w0.w;
        acc[i][4] += av[i] * w1.x; acc[i][5] += av[i] * w1.y;
        acc[i][6] += av[i] * w1.z; acc[i][7] += av[i] * w1.w;
      }
    }
    __syncthreads();
  }
  #pragma unroll
  for (int i = 0; i < 4; ++i) {
    int grow = row0 + r0 + i;
    if (grow >= M) continue;
    float4 h0 = *reinterpret_cast<const float4*>(&h[(size_t)grow * N + c0]);
    float4 h1 = *reinterpret_cast<const float4*>(&h[(size_t)grow * N + c0 + 64]);
    float4 o0 = make_float4(h0.x + LRELU(acc[i][0]), h0.y + LRELU(acc[i][1]),
                            h0.z + LRELU(acc[i][2]), h0.w + LRELU(acc[i][3]));
    float4 o1 = make_float4(h1.x + LRELU(acc[i][4]), h1.y + LRELU(acc[i][5]),
                            h1.z + LRELU(acc[i][6]), h1.w + LRELU(acc[i][7]));
    *reinterpret_cast<float4*>(&C[(size_t)grow * N + c0]) = o0;
    *reinterpret_cast<float4*>(&C[(size_t)grow * N + c0 + 64]) = o1;
  }
}

// ---------------------------------------------------------------------------
extern "C" void kernel_launch(void* const* d_in, const int* in_sizes, int n_in,
                              void* d_out, int out_size, void* d_ws, size_t ws_size,
                              hipStream_t stream) {
  const float* f_feat   = (const float*)d_in[0];
  const float* r_feat   = (const float*)d_in[1];
  const float* ff_efeat = (const float*)d_in[2];
  const float* rr_efeat = (const float*)d_in[3];
  const float* rf_efeat = (const float*)d_in[4];
  const float* Wf     = (const float*)d_in[5];
  const float* Wr     = (const float*)d_in[6];
  const float* We_ff  = (const float*)d_in[7];
  const float* We_rr  = (const float*)d_in[8];
  const float* We_rf  = (const float*)d_in[9];
  const float* a_ff   = (const float*)d_in[10];
  const float* a_rr   = (const float*)d_in[11];
  const float* a_rf   = (const float*)d_in[12];
  const float* Wec_ff = (const float*)d_in[13];
  const float* Wec_rr = (const float*)d_in[14];
  const float* Wec_rf = (const float*)d_in[15];
  const float* Wnc_ff = (const float*)d_in[16];
  const float* Wnc_rr = (const float*)d_in[17];
  const float* Wnc_rf = (const float*)d_in[18];
  const int* ff_src = (const int*)d_in[19];
  const int* ff_dst = (const int*)d_in[20];
  const int* rr_src = (const int*)d_in[21];
  const int* rr_dst = (const int*)d_in[22];
  const int* rf_src = (const int*)d_in[23];
  const int* rf_dst = (const int*)d_in[24];

  float* out = (float*)d_out;
  float* ws  = (float*)d_ws;
  int*   wsI = (int*)(ws + WS_INT);

  float* hf     = ws + WS_HF;
  float* hr     = ws + WS_HR;
  float* gfc_ff = ws + WS_GFC_FF;
  float* gfc_rf = ws + WS_GFC_RF;
  float* grc_rr = ws + WS_GRC_RR;
  float* wt     = ws + WS_WT;
  float* sum_f  = ws + WS_SUMF;
  float* sum_r  = ws + WS_SUMR;
  float* agg_f  = ws + WS_AGGF;
  float* agg_r  = ws + WS_AGGR;

  int* cur_ff = wsI + I_CUR_FF;
  int* cur_rf = wsI + I_CUR_RF;
  int* cur_rr = wsI + I_CUR_RR;
  int* off_ff = wsI + I_OFF_FF;
  int* off_rf = wsI + I_OFF_RF;
  int* off_rr = wsI + I_OFF_RR;
  int* eid_ff = wsI + I_EID_FF;
  int* eid_rf = wsI + I_EID_RF;
  int* eid_rr = wsI + I_EID_RR;

  float* out_eff = out + OFF_EFF;
  float* out_err = out + OFF_ERR;
  float* out_erf = out + OFF_ERF;

  // zero CSR histograms
  hipMemsetAsync(wsI, 0, I_ZERO_CNT * sizeof(int), stream);

  // w̃ = We @ a_e (tiny)
  wtilde_k<<<1, 192, 0, stream>>>(We_ff, We_rr, We_rf, a_ff, a_rr, a_rf, wt);

  // CSR build (by dst) for the three edge types
  hist_k<<<(E_FF + 255) / 256, 256, 0, stream>>>(ff_dst, cur_ff, E_FF);
  hist_k<<<(E_RF + 255) / 256, 256, 0, stream>>>(rf_dst, cur_rf, E_RF);
  hist_k<<<(E_RR + 255) / 256, 256, 0, stream>>>(rr_dst, cur_rr, E_RR);
  scan_k<<<1, 1024, 0, stream>>>(cur_ff, off_ff, N_F);
  scan_k<<<1, 1024, 0, stream>>>(cur_rf, off_rf, N_F);
  scan_k<<<1, 1024, 0, stream>>>(cur_rr, off_rr, N_R);
  fill_k<<<(E_FF + 255) / 256, 256, 0, stream>>>(ff_dst, cur_ff, eid_ff, E_FF);
  fill_k<<<(E_RF + 255) / 256, 256, 0, stream>>>(rf_dst, cur_rf, eid_rf, E_RF);
  fill_k<<<(E_RR + 255) / 256, 256, 0, stream>>>(rr_dst, cur_rr, eid_rr, E_RR);

  // node projections fused with the 3 per-node attention dots
  gemm_dot3_128<<<(N_F + 63) / 64, 256, 0, stream>>>(
      f_feat, Wf, a_ff, a_ff + 128, a_rf + 128, hf,
      ws + WS_DF_FFS, ws + WS_DF_FFD, ws + WS_DF_RFD, N_F);
  gemm_dot3_128<<<(N_R + 63) / 64, 256, 0, stream>>>(
      r_feat, Wr, a_rr, a_rr + 128, a_rf, hr,
      ws + WS_DR_RRS, ws + WS_DR_RRD, ws + WS_DR_RFS, N_R);

  // edge-converter projections
  gemm_128x64<<<(N_F + 63) / 64, 256, 0, stream>>>(hf, Wec_ff, gfc_ff, N_F);
  gemm_128x64<<<(N_F + 63) / 64, 256, 0, stream>>>(hf, Wec_rf, gfc_rf, N_F);
  gemm_128x64<<<(N_R + 63) / 64, 256, 0, stream>>>(hr, Wec_rr, grc_rr, N_R);

  // scores from RAW efeat (projection folded into w̃), no atomics
  score_edge_k<<<(E_FF * 16 + 255) / 256, 256, 0, stream>>>(
      ff_efeat, wt, ws + WS_DF_FFS, ws + WS_DF_FFD, ff_src, ff_dst,
      ws + WS_SFF, E_FF);
  score_edge_k<<<(E_RR * 16 + 255) / 256, 256, 0, stream>>>(
      rr_efeat, wt + 64, ws + WS_DR_RRS, ws + WS_DR_RRD, rr_src, rr_dst,
      ws + WS_SRR, E_RR);
  score_edge_k<<<(E_RF * 16 + 255) / 256, 256, 0, stream>>>(
      rf_efeat, wt + 128, ws + WS_DR_RFS, ws + WS_DF_RFD, rf_src, rf_dst,
      ws + WS_SRF, E_RF);

  // dst score sums via CSR gather (no atomics)
  sum_csr_k<<<(N_F + 255) / 256, 256, 0, stream>>>(
      off_ff, eid_ff, ws + WS_SFF, off_rf, eid_rf, ws + WS_SRF, sum_f, N_F);
  sum_csr_k<<<(N_R + 255) / 256, 256, 0, stream>>>(
      off_rr, eid_rr, ws + WS_SRR, nullptr, nullptr, nullptr, sum_r, N_R);

  // fused projection + edge update (write-once, no scatter)
  edge_proj_upd_k<<<(E_FF + 127) / 128, 256, 0, stream>>>(
      ff_efeat, We_ff, gfc_ff, ws + WS_SFF, sum_f, ff_src, ff_dst, out_eff, E_FF);
  edge_proj_upd_k<<<(E_RR + 127) / 128, 256, 0, stream>>>(
      rr_efeat, We_rr, grc_rr, ws + WS_SRR, sum_r, rr_src, rr_dst, out_err, E_RR);
  edge_proj_upd_k<<<(E_RF + 127) / 128, 256, 0, stream>>>(
      rf_efeat, We_rf, gfc_rf, ws + WS_SRF, sum_r, rf_src, rf_dst, out_erf, E_RF);

  // CSR aggregation: one wave per dst node (latency hidden by TLP)
  agg_f_k<<<(N_F + 3) / 4, 256, 0, stream>>>(
      out_eff, out_erf, off_ff, eid_ff, off_rf, eid_rf, agg_f, N_F);
  agg_r_k<<<(N_R + 3) / 4, 256, 0, stream>>>(
      out_err, off_rr, eid_rr, agg_r, N_R);

  // dense node-update GEMMs
  node_update_k<128><<<(N_F + 63) / 64, 256, 0, stream>>>(
      agg_f, Wnc_ff, Wnc_rf, hf, out + OFF_NF, N_F);
  node_update_k<64><<<(N_R + 63) / 64, 256, 0, stream>>>(
      agg_r, Wnc_rr, nullptr, hr, out + OFF_NR, N_R);
}